// Round 4
// baseline (187.687 us; speedup 1.0000x reference)
//
#include <hip/hip_runtime.h>

// Discounted cumulative return y[t] = r[t] + a[t]*y[t+1], a[t]=terminal[t]?0:0.99
// Round 11 = Round 10 kernel + ONE change: nontemporal (no-allocate) stores for
// the out stream in k_local's fast path. Theory: FETCH_SIZE (65.6MB) == output
// size exactly, while app reads (134MB) are L3-warm -> the HBM fetches are
// write-allocate/RFO on out. NT stores skip the allocate; predicted FETCH -> <10MB,
// k_local 64 -> ~45-52us. Everything else identical to R10 for clean attribution.
//
//   K1: in-block scan with y_in=0 -> out, per-block aggregate (A,B) + last
//       terminal index. Inputs read once.
//   K2: per-block compose of aggregates above -> y_in; correction
//       out[i] += 0.99^(hi+1-i) * y_in only past the block's last terminal.
//
// Affine F(x)=A*x+B maps y[hi+1]->y[lo]; compose outer = lower indices:
// (A1,B1)o(A2,B2) = (A1*A2, A1*B2+B1).

constexpr int   TPB   = 256;
constexpr int   IPTC  = 8;               // elems per thread per chunk
constexpr int   NCH   = 4;               // chunks per block
constexpr int   CHUNK = TPB * IPTC;      // 2048
constexpr int   TILE  = CHUNK * NCH;     // 8192 elems per block
constexpr float DISC  = 0.99f;
constexpr float L2DISC = -0.0144995696f; // log2(0.99)

typedef float vf4 __attribute__((ext_vector_type(4)));   // nontemporal-storable

// Inclusive wave SUFFIX scan: lane l ends with F_l o F_{l+1} o ... o F_63.
__device__ __forceinline__ void wave_suffix_scan(float& A, float& B, int lane) {
    #pragma unroll
    for (int off = 1; off < 64; off <<= 1) {
        float oA = __shfl_down(A, off, 64);
        float oB = __shfl_down(B, off, 64);
        if (lane + off < 64) { B = A * oB + B; A = A * oA; }
    }
}

// K1: local scan (y_in = 0) -> out; write agg[b] and lastT[b].
__global__ __launch_bounds__(TPB) void k_local(
        const int* __restrict__ term, const float* __restrict__ rew,
        float* __restrict__ out, float2* __restrict__ agg,
        int* __restrict__ lastT, long long T) {
    __shared__ float2 sWA[2][TPB / 64];
    __shared__ int    sLast[2][TPB / 64];

    const int t = threadIdx.x;
    const int lane = t & 63, wav = t >> 6;
    const int b = blockIdx.x;
    const long long lo = (long long)b * TILE;
    const bool fastblk = (lo + TILE <= T);

    float At = 1.f, Bt = 0.f;   // block aggregate over processed (higher) chunks
    int   lt = -1;              // last terminal global index in block

    if (fastblk) {
        float4 bR[NCH][IPTC / 4];
        int4   bT[NCH][IPTC / 4];

        // Issue all chunk loads up front, highest chunk first.
        #pragma unroll
        for (int c = NCH - 1; c >= 0; --c) {
            const long long base = lo + (long long)c * CHUNK + (long long)t * IPTC;
            const float4* rp = (const float4*)(rew + base);
            const int4*   tp = (const int4*)(term + base);
            #pragma unroll
            for (int q = 0; q < IPTC / 4; ++q) {
                bR[c][q] = rp[q];
                bT[c][q] = tp[q];
            }
        }

        #pragma unroll
        for (int c = NCH - 1; c >= 0; --c) {
            const int pb = c & 1;                 // LDS buffer parity
            const long long base = lo + (long long)c * CHUNK + (long long)t * IPTC;

            float r[IPTC];
            unsigned mask = 0;
            #pragma unroll
            for (int q = 0; q < IPTC / 4; ++q) {
                float4 rv = bR[c][q];
                int4   tv = bT[c][q];
                r[4*q+0] = rv.x; r[4*q+1] = rv.y; r[4*q+2] = rv.z; r[4*q+3] = rv.w;
                mask |= (tv.x ? 1u : 0u) << (4*q+0);
                mask |= (tv.y ? 1u : 0u) << (4*q+1);
                mask |= (tv.z ? 1u : 0u) << (4*q+2);
                mask |= (tv.w ? 1u : 0u) << (4*q+3);
            }

            // thread-local compose, high->low
            float A = 1.f, B = 0.f;
            #pragma unroll
            for (int k = IPTC - 1; k >= 0; --k) {
                float ak = ((mask >> k) & 1u) ? 0.f : DISC;
                B = ak * B + r[k]; A = ak * A;
            }

            float IA = A, IB = B;
            wave_suffix_scan(IA, IB, lane);

            int myLast = mask ? (int)(base + (31 - __clz(mask))) : -1;
            #pragma unroll
            for (int off = 32; off > 0; off >>= 1)
                myLast = max(myLast, __shfl_down(myLast, off, 64));

            if (lane == 0) { sWA[pb][wav] = make_float2(IA, IB); sLast[pb][wav] = myLast; }
            __syncthreads();

            // chunk aggregate + exclusives (all threads, redundant & cheap)
            float2 g = sWA[pb][0];
            int cl = sLast[pb][0];
            #pragma unroll
            for (int w = 1; w < TPB / 64; ++w) {
                float2 h = sWA[pb][w];
                g.y = g.x * h.y + g.y; g.x = g.x * h.x;
                cl = max(cl, sLast[pb][w]);
            }
            float EWA = 1.f, EWB = 0.f;
            #pragma unroll
            for (int w = 0; w < TPB / 64; ++w)
                if (w > wav) { float2 h = sWA[pb][w]; EWB = EWA*h.y + EWB; EWA = EWA*h.x; }

            float EA = __shfl_down(IA, 1, 64);
            float EB = __shfl_down(IB, 1, 64);
            if (lane == 63) { EA = 1.f; EB = 0.f; }

            const float Yc = Bt;              // y entering this chunk from above
            float y = EA * (EWA * Yc + EWB) + EB;

            #pragma unroll
            for (int k = IPTC - 1; k >= 0; --k) {
                float ak = ((mask >> k) & 1u) ? 0.f : DISC;
                y = ak * y + r[k]; r[k] = y;
            }

            // NT stores: skip L2/L3 write-allocate (suspected RFO = 65MB fetch)
            vf4* op = (vf4*)(out + base);
            #pragma unroll
            for (int q = 0; q < IPTC / 4; ++q) {
                vf4 v = { r[4*q+0], r[4*q+1], r[4*q+2], r[4*q+3] };
                __builtin_nontemporal_store(v, op + q);
            }

            // fold chunk into block aggregate: F_new = F_c o F_prev
            Bt = g.x * Bt + g.y;
            At = g.x * At;
            lt = max(lt, cl);
        }
    } else {
        // guarded tail block (only the last block when T % TILE != 0)
        for (int c = NCH - 1; c >= 0; --c) {
            const int pb = c & 1;
            const long long base = lo + (long long)c * CHUNK + (long long)t * IPTC;
            float r[IPTC];
            unsigned mask = 0;
            #pragma unroll
            for (int k = 0; k < IPTC; ++k) {
                long long i = base + k;
                if (i < T) { r[k] = rew[i]; mask |= (term[i] ? 1u : 0u) << k; }
                else       { r[k] = 0.f; }
            }
            float A = 1.f, B = 0.f;
            #pragma unroll
            for (int k = IPTC - 1; k >= 0; --k) {
                float ak = ((mask >> k) & 1u) ? 0.f : DISC;
                if (base + k >= T) ak = 1.f;
                B = ak * B + r[k]; A = ak * A;
            }
            float IA = A, IB = B;
            wave_suffix_scan(IA, IB, lane);

            int myLast = mask ? (int)(base + (31 - __clz(mask))) : -1;
            #pragma unroll
            for (int off = 32; off > 0; off >>= 1)
                myLast = max(myLast, __shfl_down(myLast, off, 64));

            if (lane == 0) { sWA[pb][wav] = make_float2(IA, IB); sLast[pb][wav] = myLast; }
            __syncthreads();

            float2 g = sWA[pb][0];
            int cl = sLast[pb][0];
            #pragma unroll
            for (int w = 1; w < TPB / 64; ++w) {
                float2 h = sWA[pb][w];
                g.y = g.x * h.y + g.y; g.x = g.x * h.x;
                cl = max(cl, sLast[pb][w]);
            }
            float EWA = 1.f, EWB = 0.f;
            #pragma unroll
            for (int w = 0; w < TPB / 64; ++w)
                if (w > wav) { float2 h = sWA[pb][w]; EWB = EWA*h.y + EWB; EWA = EWA*h.x; }

            float EA = __shfl_down(IA, 1, 64);
            float EB = __shfl_down(IB, 1, 64);
            if (lane == 63) { EA = 1.f; EB = 0.f; }

            const float Yc = Bt;
            float y = EA * (EWA * Yc + EWB) + EB;

            #pragma unroll
            for (int k = IPTC - 1; k >= 0; --k) {
                float ak = ((mask >> k) & 1u) ? 0.f : DISC;
                if (base + k >= T) ak = 1.f;
                y = ak * y + r[k]; r[k] = y;
            }
            #pragma unroll
            for (int k = 0; k < IPTC; ++k) {
                long long i = base + k;
                if (i < T) out[i] = r[k];
            }

            Bt = g.x * Bt + g.y;
            At = g.x * At;
            lt = max(lt, cl);
        }
    }

    if (t == 0) {
        agg[b] = make_float2(At, Bt);
        lastT[b] = max(lt, (int)lo - 1);   // lo-1 == "no terminal in block"
    }
}

// K2: per-block y_in from aggregates above, then sparse tail correction.
__global__ __launch_bounds__(TPB) void k_fix(
        const float2* __restrict__ agg, const int* __restrict__ lastT,
        float* __restrict__ out, int numBlocks, long long T) {
    __shared__ float2 sWB[TPB / 64];

    const int t = threadIdx.x;
    const int lane = t & 63, wav = t >> 6;
    const int b = blockIdx.x;

    const int cpt = (numBlocks + TPB - 1) / TPB;     // 8 for 2048
    float VA = 1.f, VB = 0.f;
    #pragma unroll
    for (int k = cpt - 1; k >= 0; --k) {             // descending g: inner first
        int g = t * cpt + k;
        if (g > b && g < numBlocks) {
            float2 q = agg[g];
            VB = q.x * VB + q.y; VA = q.x * VA;
        }
    }
    wave_suffix_scan(VA, VB, lane);
    if (lane == 0) sWB[wav] = make_float2(VA, VB);
    __syncthreads();

    float FA = sWB[0].x, FB = sWB[0].y;              // wave 0 outermost
    #pragma unroll
    for (int w = 1; w < TPB / 64; ++w) {
        float2 h = sWB[w];
        FB = FA * h.y + FB; FA = FA * h.x;
    }
    const float yin = FB;                            // y entering block b (x=0)
    if (yin == 0.f) return;

    const long long lo = (long long)b * TILE;
    const long long hi = min(lo + TILE, T) - 1;
    const long long start = (long long)lastT[b] + 1; // >= lo by construction

    for (long long i = start + t; i <= hi; i += TPB) {
        float d = (float)(int)(hi + 1 - i);
        out[i] += exp2f(d * L2DISC) * yin;
    }
}

extern "C" void kernel_launch(void* const* d_in, const int* in_sizes, int n_in,
                              void* d_out, int out_size, void* d_ws, size_t ws_size,
                              hipStream_t stream) {
    const int*   term = (const int*)d_in[0];
    const float* rew  = (const float*)d_in[1];
    float*       out  = (float*)d_out;

    const long long T = (long long)in_sizes[1];
    const int numBlocks = (int)((T + TILE - 1) / TILE);   // 2048 for T=2^24

    float2* agg   = (float2*)d_ws;
    int*    lastT = (int*)(agg + numBlocks);

    k_local<<<numBlocks, TPB, 0, stream>>>(term, rew, out, agg, lastT, T);
    k_fix  <<<numBlocks, TPB, 0, stream>>>(agg, lastT, out, numBlocks, T);
}

// Round 5
// 175.966 us; speedup vs baseline: 1.0666x; 1.0666x over previous
//
#include <hip/hip_runtime.h>

// Discounted cumulative return y[t] = r[t] + a[t]*y[t+1], a[t]=terminal[t]?0:0.99
// Round 12: NT stores REVERTED (R11: FETCH unchanged -> not RFO; WRITE +7MB and
// k_fix +7us from L2 eviction). New single variable: TPB=1024 (16 waves/block),
// NCH=1 -> ONE barrier per block. TILE stays 8192 so traffic and k_fix are
// identical to the 178us baseline. Theory: scheduler co-locates only ~2-3
// workgroups/CU (measured occupancy 32% across 3 kernels with VGPR=60); fat
// blocks make 1-2 resident workgroups = 50-100% occupancy, restoring the
// latency-hiding parallelism that lets copy-style kernels reach ~6.3 TB/s.
//
//   K1: in-block scan with y_in=0 -> out, per-block aggregate (A,B) + last
//       terminal index. Inputs read once.
//   K2: per-block compose of aggregates above -> y_in; correction
//       out[i] += 0.99^(hi+1-i) * y_in only past the block's last terminal.
//
// Affine F(x)=A*x+B maps y[hi+1]->y[lo]; compose outer = lower indices:
// (A1,B1)o(A2,B2) = (A1*A2, A1*B2+B1).

constexpr int   TPB   = 1024;            // 16 waves
constexpr int   NWAV  = TPB / 64;        // 16
constexpr int   IPTC  = 8;               // elems per thread
constexpr int   TILE  = TPB * IPTC;      // 8192 elems per block (same as before)
constexpr float DISC  = 0.99f;
constexpr float L2DISC = -0.0144995696f; // log2(0.99)

constexpr int   FTPB  = 256;             // k_fix block size (unchanged)

// Inclusive wave SUFFIX scan: lane l ends with F_l o F_{l+1} o ... o F_63.
__device__ __forceinline__ void wave_suffix_scan(float& A, float& B, int lane) {
    #pragma unroll
    for (int off = 1; off < 64; off <<= 1) {
        float oA = __shfl_down(A, off, 64);
        float oB = __shfl_down(B, off, 64);
        if (lane + off < 64) { B = A * oB + B; A = A * oA; }
    }
}

// K1: local scan (y_in = 0) -> out; write agg[b] and lastT[b].
__global__ __launch_bounds__(TPB) void k_local(
        const int* __restrict__ term, const float* __restrict__ rew,
        float* __restrict__ out, float2* __restrict__ agg,
        int* __restrict__ lastT, long long T) {
    __shared__ float2 sWA[NWAV];
    __shared__ int    sLast[NWAV];

    const int t = threadIdx.x;
    const int lane = t & 63, wav = t >> 6;
    const int b = blockIdx.x;
    const long long lo = (long long)b * TILE;
    const bool fastblk = (lo + TILE <= T);

    float At, Bt;               // block aggregate
    int   lt;                   // last terminal global index in block

    if (fastblk) {
        const long long base = lo + (long long)t * IPTC;

        float4 bR[IPTC / 4];
        int4   bT[IPTC / 4];
        {
            const float4* rp = (const float4*)(rew + base);
            const int4*   tp = (const int4*)(term + base);
            #pragma unroll
            for (int q = 0; q < IPTC / 4; ++q) {
                bR[q] = rp[q];
                bT[q] = tp[q];
            }
        }

        float r[IPTC];
        unsigned mask = 0;
        #pragma unroll
        for (int q = 0; q < IPTC / 4; ++q) {
            float4 rv = bR[q];
            int4   tv = bT[q];
            r[4*q+0] = rv.x; r[4*q+1] = rv.y; r[4*q+2] = rv.z; r[4*q+3] = rv.w;
            mask |= (tv.x ? 1u : 0u) << (4*q+0);
            mask |= (tv.y ? 1u : 0u) << (4*q+1);
            mask |= (tv.z ? 1u : 0u) << (4*q+2);
            mask |= (tv.w ? 1u : 0u) << (4*q+3);
        }

        // thread-local compose, high->low
        float A = 1.f, B = 0.f;
        #pragma unroll
        for (int k = IPTC - 1; k >= 0; --k) {
            float ak = ((mask >> k) & 1u) ? 0.f : DISC;
            B = ak * B + r[k]; A = ak * A;
        }

        float IA = A, IB = B;
        wave_suffix_scan(IA, IB, lane);

        int myLast = mask ? (int)(base + (31 - __clz(mask))) : -1;
        #pragma unroll
        for (int off = 32; off > 0; off >>= 1)
            myLast = max(myLast, __shfl_down(myLast, off, 64));

        if (lane == 0) { sWA[wav] = make_float2(IA, IB); sLast[wav] = myLast; }
        __syncthreads();   // the ONLY barrier in the block

        // block aggregate + per-wave exclusives (all threads, redundant & cheap)
        float2 g = sWA[0];
        int cl = sLast[0];
        #pragma unroll
        for (int w = 1; w < NWAV; ++w) {
            float2 h = sWA[w];
            g.y = g.x * h.y + g.y; g.x = g.x * h.x;
            cl = max(cl, sLast[w]);
        }
        float EWA = 1.f, EWB = 0.f;
        #pragma unroll
        for (int w = 0; w < NWAV; ++w)
            if (w > wav) { float2 h = sWA[w]; EWB = EWA*h.y + EWB; EWA = EWA*h.x; }

        float EA = __shfl_down(IA, 1, 64);
        float EB = __shfl_down(IB, 1, 64);
        if (lane == 63) { EA = 1.f; EB = 0.f; }

        // y entering this thread's span (block-level y_in = 0)
        float y = EA * EWB + EB;

        #pragma unroll
        for (int k = IPTC - 1; k >= 0; --k) {
            float ak = ((mask >> k) & 1u) ? 0.f : DISC;
            y = ak * y + r[k]; r[k] = y;
        }

        float4* op = (float4*)(out + base);
        #pragma unroll
        for (int q = 0; q < IPTC / 4; ++q)
            op[q] = make_float4(r[4*q+0], r[4*q+1], r[4*q+2], r[4*q+3]);

        At = g.x; Bt = g.y; lt = cl;
    } else {
        // guarded tail block (only the last block when T % TILE != 0)
        const long long base = lo + (long long)t * IPTC;
        float r[IPTC];
        unsigned mask = 0;
        #pragma unroll
        for (int k = 0; k < IPTC; ++k) {
            long long i = base + k;
            if (i < T) { r[k] = rew[i]; mask |= (term[i] ? 1u : 0u) << k; }
            else       { r[k] = 0.f; }
        }
        float A = 1.f, B = 0.f;
        #pragma unroll
        for (int k = IPTC - 1; k >= 0; --k) {
            float ak = ((mask >> k) & 1u) ? 0.f : DISC;
            if (base + k >= T) ak = 1.f;
            B = ak * B + r[k]; A = ak * A;
        }
        float IA = A, IB = B;
        wave_suffix_scan(IA, IB, lane);

        int myLast = mask ? (int)(base + (31 - __clz(mask))) : -1;
        #pragma unroll
        for (int off = 32; off > 0; off >>= 1)
            myLast = max(myLast, __shfl_down(myLast, off, 64));

        if (lane == 0) { sWA[wav] = make_float2(IA, IB); sLast[wav] = myLast; }
        __syncthreads();

        float2 g = sWA[0];
        int cl = sLast[0];
        #pragma unroll
        for (int w = 1; w < NWAV; ++w) {
            float2 h = sWA[w];
            g.y = g.x * h.y + g.y; g.x = g.x * h.x;
            cl = max(cl, sLast[w]);
        }
        float EWA = 1.f, EWB = 0.f;
        #pragma unroll
        for (int w = 0; w < NWAV; ++w)
            if (w > wav) { float2 h = sWA[w]; EWB = EWA*h.y + EWB; EWA = EWA*h.x; }

        float EA = __shfl_down(IA, 1, 64);
        float EB = __shfl_down(IB, 1, 64);
        if (lane == 63) { EA = 1.f; EB = 0.f; }

        float y = EA * EWB + EB;

        #pragma unroll
        for (int k = IPTC - 1; k >= 0; --k) {
            float ak = ((mask >> k) & 1u) ? 0.f : DISC;
            if (base + k >= T) ak = 1.f;
            y = ak * y + r[k]; r[k] = y;
        }
        #pragma unroll
        for (int k = 0; k < IPTC; ++k) {
            long long i = base + k;
            if (i < T) out[i] = r[k];
        }

        At = g.x; Bt = g.y; lt = cl;
    }

    if (t == 0) {
        agg[b] = make_float2(At, Bt);
        lastT[b] = max(lt, (int)lo - 1);   // lo-1 == "no terminal in block"
    }
}

// K2: per-block y_in from aggregates above, then sparse tail correction.
__global__ __launch_bounds__(FTPB) void k_fix(
        const float2* __restrict__ agg, const int* __restrict__ lastT,
        float* __restrict__ out, int numBlocks, long long T) {
    __shared__ float2 sWB[FTPB / 64];

    const int t = threadIdx.x;
    const int lane = t & 63, wav = t >> 6;
    const int b = blockIdx.x;

    const int cpt = (numBlocks + FTPB - 1) / FTPB;   // 8 for 2048
    float VA = 1.f, VB = 0.f;
    #pragma unroll
    for (int k = cpt - 1; k >= 0; --k) {             // descending g: inner first
        int g = t * cpt + k;
        if (g > b && g < numBlocks) {
            float2 q = agg[g];
            VB = q.x * VB + q.y; VA = q.x * VA;
        }
    }
    wave_suffix_scan(VA, VB, lane);
    if (lane == 0) sWB[wav] = make_float2(VA, VB);
    __syncthreads();

    float FA = sWB[0].x, FB = sWB[0].y;              // wave 0 outermost
    #pragma unroll
    for (int w = 1; w < FTPB / 64; ++w) {
        float2 h = sWB[w];
        FB = FA * h.y + FB; FA = FA * h.x;
    }
    const float yin = FB;                            // y entering block b (x=0)
    if (yin == 0.f) return;

    const long long lo = (long long)b * TILE;
    const long long hi = min(lo + (long long)TILE, T) - 1;
    const long long start = (long long)lastT[b] + 1; // >= lo by construction

    for (long long i = start + t; i <= hi; i += FTPB) {
        float d = (float)(int)(hi + 1 - i);
        out[i] += exp2f(d * L2DISC) * yin;
    }
}

extern "C" void kernel_launch(void* const* d_in, const int* in_sizes, int n_in,
                              void* d_out, int out_size, void* d_ws, size_t ws_size,
                              hipStream_t stream) {
    const int*   term = (const int*)d_in[0];
    const float* rew  = (const float*)d_in[1];
    float*       out  = (float*)d_out;

    const long long T = (long long)in_sizes[1];
    const int numBlocks = (int)((T + TILE - 1) / TILE);   // 2048 for T=2^24

    float2* agg   = (float2*)d_ws;
    int*    lastT = (int*)(agg + numBlocks);

    k_local<<<numBlocks, TPB, 0, stream>>>(term, rew, out, agg, lastT, T);
    k_fix  <<<numBlocks, FTPB, 0, stream>>>(agg, lastT, out, numBlocks, T);
}